// Round 6
// baseline (250.226 us; speedup 1.0000x reference)
//
#include <hip/hip_runtime.h>
#include <math.h>

// S4D forward (conv mode) via chunked linear recurrence.
// y[b,l,d] = D[d]*x[b,l,d] + sum_n CB[d,n] * h_n[l],  h_n[l] = a_n h_n[l-1] + x[l]
// a = exp(dt*A), CB = C * expm1(dt*A)/A * B, A_n = -0.5*(n+1)
//
// Empirical law from R0-R5: the ONLY structure that avoids catastrophic
// scratch spill is { load xv[T] in a plain unrolled loop at the top; rolled
// n-group loop; fully-unrolled t-loop } -> compiler parks xv/acc in AGPRs.
// R5 post-mortem: out at T=64/NG=8 has 232 unified regs -> 2 waves/SIMD ->
// 50% latency stall. This round: out at T=32 (64 AGPR + ~45 VGPR -> 3-4
// waves/SIMD, issue bound ~34us) fed WITHOUT doubling scan/state chunking:
//   - state (T=64) also writes the zero-init MID-chunk state umid (+67 MB).
//   - scan (unchanged 32 steps over u64) additionally transforms in place
//     umid[c] <- a32*s + umid[c]  (a32 = sqrt(aT)), so u64/umid hold the
//     start states of half-chunks 2c / 2c+1.
//   - out (T=32, NG=8, R1-proven skeleton) picks its start state by a pure
//     address offset hc*kUMid -- no new control flow, no spill risk.
// Workspace: 2*16,777,216 + 3*65,536 floats = 135,004,160 B (== R1 proven).

namespace {
constexpr int kBatch = 8;
constexpr int kLen   = 2048;
constexpr int kD     = 1024;
constexpr int kN     = 64;         // states
constexpr int kT     = 64;         // state/scan chunk length
constexpr int kC     = kLen / kT;  // 32 chunks
constexpr int kTO    = 32;         // out-kernel half-chunk length

constexpr long kHalf  = (long)kBatch * kC * kN * kD;  // 16,777,216 floats
constexpr long kUMid  = kHalf;                        // umid region offset
constexpr long kAOff  = 2 * kHalf;                    // a[n][d]
constexpr long kCbOff = kAOff + (long)kN * kD;        // cb[n][d]
constexpr long kAtOff = kCbOff + (long)kN * kD;       // a^64[n][d]
// total ws: (33,554,432 + 196,608) * 4 B = 135,004,160 B
}  // namespace

__global__ void s4d_coef_kernel(const float* __restrict__ log_dt,
                                const float* __restrict__ Bm,
                                const float* __restrict__ Cm,
                                float* __restrict__ ws) {
  int tid = blockIdx.x * blockDim.x + threadIdx.x;  // 65536 threads
  int d = tid & (kD - 1);
  int n = tid >> 10;
  float dt  = expf(log_dt[d]);
  float An  = -0.5f * (float)(n + 1);
  float dtA = dt * An;
  float a   = expf(dtA);
  float bbar = (expm1f(dtA) / An) * Bm[d * kN + n];
  float cb   = Cm[d * kN + n] * bbar;
  float aT   = expf(dtA * (float)kT);  // a^64
  ws[kAOff  + (long)n * kD + d] = a;
  ws[kCbOff + (long)n * kD + d] = cb;
  ws[kAtOff + (long)n * kD + d] = aT;
}

// Phase 1: chunk-local zero-init states at T=64 chunking. Writes BOTH the
// mid-chunk state (after 32 steps) and the end-of-chunk state. R5-proven
// skeleton: xv[64] AGPR-parked, NG=8 h-chains share each xv read.
__global__ __launch_bounds__(256) void s4d_state_kernel(
    const float* __restrict__ x, float* __restrict__ ws) {
  constexpr int NG = 8;
  int tid = blockIdx.x * blockDim.x + threadIdx.x;  // 262144 threads
  int d  = tid & (kD - 1);   // consecutive lanes -> consecutive d: coalesced
  int bc = tid >> 10;
  int b  = bc >> 5;
  int c  = bc & (kC - 1);

  const float* xp = x + ((long)b * kLen + (long)c * kT) * kD + d;
  float xv[kT];
#pragma unroll
  for (int t = 0; t < kT; ++t) xv[t] = xp[(long)t * kD];

  const float* ap = ws + kAOff + d;
  float* u64p  = ws + ((long)bc * kN) * kD + d;
  float* umidp = u64p + kUMid;
#pragma unroll 1
  for (int g = 0; g < kN; g += NG) {
    float a[NG], h[NG];
#pragma unroll
    for (int i = 0; i < NG; ++i) {
      a[i] = ap[(long)(g + i) * kD];
      h[i] = 0.f;
    }
#pragma unroll
    for (int t = 0; t < kTO; ++t) {  // first half
      float xt = xv[t];
#pragma unroll
      for (int i = 0; i < NG; ++i) h[i] = fmaf(h[i], a[i], xt);
    }
#pragma unroll
    for (int i = 0; i < NG; ++i) umidp[(long)(g + i) * kD] = h[i];
#pragma unroll
    for (int t = kTO; t < kT; ++t) {  // second half (continues the chain)
      float xt = xv[t];
#pragma unroll
      for (int i = 0; i < NG; ++i) h[i] = fmaf(h[i], a[i], xt);
    }
#pragma unroll
    for (int i = 0; i < NG; ++i) u64p[(long)(g + i) * kD] = h[i];
  }
}

// Phase 2: inter-chunk scan over u64 (32 steps, unchanged chain) that ALSO
// materializes the half-chunk start states in place:
//   u64[c]  <- s64[c]                 (start of half 2c)
//   umid[c] <- a32*s64[c] + umid[c]   (start of half 2c+1; a32 = sqrt(aT))
__global__ void s4d_scan_kernel(float* __restrict__ ws) {
  int tid = blockIdx.x * blockDim.x + threadIdx.x;  // 524288 threads
  int d  = tid & (kD - 1);
  int bn = tid >> 10;
  int n  = bn & (kN - 1);
  int b  = bn >> 6;
  float aT  = ws[kAtOff + (long)n * kD + d];
  float a32 = sqrtf(aT);  // exact to ~1 ulp; underflow cases are harmless
  float* u64p  = ws + ((long)b * kC * kN + n) * kD + d;
  float* umidp = u64p + kUMid;
  const long cstride = (long)kN * kD;
  float s = 0.f;
#pragma unroll 1
  for (int c = 0; c < kC; ++c) {
    float u = u64p[(long)c * cstride];
    float m = umidp[(long)c * cstride];
    u64p[(long)c * cstride]  = s;
    umidp[(long)c * cstride] = fmaf(a32, s, m);
    s = fmaf(aT, s, u);
  }
}

// Phase 3: full output at T=32 half-chunks. R1-proven parking skeleton
// (xv[32]+acc[32] AGPR-parked) + R5-proven NG=8 widening. Start state is
// selected purely by address: hc=0 -> u64 region, hc=1 -> umid region.
__global__ __launch_bounds__(256, 3) void s4d_out_kernel(
    const float* __restrict__ x, const float* __restrict__ Dv,
    float* __restrict__ y, const float* __restrict__ ws) {
  constexpr int NG = 8;
  int tid = blockIdx.x * blockDim.x + threadIdx.x;  // 524288 threads
  int d  = tid & (kD - 1);
  int j  = tid >> 10;       // 0..511
  int b  = j >> 6;
  int r  = j & 63;
  int c  = r >> 1;
  int hc = r & 1;

  const float* xp =
      x + ((long)b * kLen + (long)c * kT + (long)hc * kTO) * kD + d;
  float xv[kTO];
#pragma unroll
  for (int t = 0; t < kTO; ++t) xv[t] = xp[(long)t * kD];

  float Dd = Dv[d];
  float acc[kTO];
#pragma unroll
  for (int t = 0; t < kTO; ++t) acc[t] = Dd * xv[t];

  const float* ap  = ws + kAOff + d;
  const float* cbp = ws + kCbOff + d;
  const float* sp  = ws + (long)hc * kUMid + ((long)(b * kC + c) * kN) * kD + d;

#pragma unroll 1
  for (int g = 0; g < kN; g += NG) {
    float a[NG], cb[NG], h[NG];
#pragma unroll
    for (int i = 0; i < NG; ++i) {
      long o = (long)(g + i) * kD;
      a[i]  = ap[o];
      cb[i] = cbp[o];
      h[i]  = sp[o];  // start state for this half-chunk
    }
#pragma unroll
    for (int t = 0; t < kTO; ++t) {
      float xt = xv[t];
      float s  = acc[t];
#pragma unroll
      for (int i = 0; i < NG; ++i) {
        h[i] = fmaf(h[i], a[i], xt);
        s    = fmaf(cb[i], h[i], s);
      }
      acc[t] = s;
    }
  }

  float* yp = y + ((long)b * kLen + (long)c * kT + (long)hc * kTO) * kD + d;
#pragma unroll
  for (int t = 0; t < kTO; ++t) yp[(long)t * kD] = acc[t];
}

extern "C" void kernel_launch(void* const* d_in, const int* in_sizes, int n_in,
                              void* d_out, int out_size, void* d_ws,
                              size_t ws_size, hipStream_t stream) {
  const float* x      = (const float*)d_in[0];
  const float* log_dt = (const float*)d_in[1];
  const float* Bm     = (const float*)d_in[2];
  const float* Cm     = (const float*)d_in[3];
  const float* Dv     = (const float*)d_in[4];
  float* y  = (float*)d_out;
  float* ws = (float*)d_ws;

  hipLaunchKernelGGL(s4d_coef_kernel, dim3((kN * kD) / 256), dim3(256), 0,
                     stream, log_dt, Bm, Cm, ws);
  hipLaunchKernelGGL(s4d_state_kernel, dim3((kBatch * kC * kD) / 256),
                     dim3(256), 0, stream, x, ws);
  hipLaunchKernelGGL(s4d_scan_kernel, dim3((kBatch * kN * kD) / 256),
                     dim3(256), 0, stream, ws);
  hipLaunchKernelGGL(s4d_out_kernel, dim3((kBatch * 2 * kC * kD) / 256),
                     dim3(256), 0, stream, x, Dv, y, ws);
}

// Round 7
// 235.284 us; speedup vs baseline: 1.0635x; 1.0635x over previous
//
#include <hip/hip_runtime.h>
#include <math.h>

// S4D forward (conv mode) via chunked linear recurrence.
// y[b,l,d] = D[d]*x[b,l,d] + sum_n CB[d,n] * h_n[l],  h_n[l] = a_n h_n[l-1] + x[l]
// a = exp(dt*A), CB = C * expm1(dt*A)/A * B, A_n = -0.5*(n+1)
//
// R6 post-mortem: out at T=32 is ~70us and near its issue floor, but
// materializing half-chunk start states cost +268 MB HBM (state umid write
// + scan r/w) -> non-out time 179us, identical to R1 (traffic-identical).
// R7: eliminate mid-state traffic entirely. The start state of half 2c+1 is
// the END state of half 2c -> compute it inside the out block via a
// producer-consumer pipeline over n-groups:
//   block = 128 d x 2 roles (wave-uniform). Role 0 (first half) processes
//   n-group g from the global s64 start and writes its ending h[8] to an
//   8 KB LDS double-buffer; role 1 (second half) consumes group g-1 one
//   phase later. 9 phases, 1 barrier each; +12.5% issue on out.
// State/scan revert to the R5-proven T=64 forms (u-region 67 MB).
// Per-phase live set matches R6's proven no-spill skeleton:
// xv[32]+acc[32] AGPR-parked + a/cb/h[8] per phase.

namespace {
constexpr int kBatch = 8;
constexpr int kLen   = 2048;
constexpr int kD     = 1024;
constexpr int kN     = 64;         // states
constexpr int kT     = 64;         // state/scan chunk length
constexpr int kC     = kLen / kT;  // 32 chunks
constexpr int kTO    = 32;         // out half-chunk length
constexpr int kNG    = 8;          // n-group size
constexpr int kG     = kN / kNG;   // 8 groups

constexpr long kU     = (long)kBatch * kC * kN * kD;  // 16,777,216 floats
constexpr long kAOff  = kU;                           // a[n][d]
constexpr long kCbOff = kAOff + (long)kN * kD;        // cb[n][d]
constexpr long kAtOff = kCbOff + (long)kN * kD;       // a^64[n][d]
// total ws: (16,777,216 + 3*65,536) * 4 B = 67,895,296 B (~64.8 MiB)
}  // namespace

__global__ void s4d_coef_kernel(const float* __restrict__ log_dt,
                                const float* __restrict__ Bm,
                                const float* __restrict__ Cm,
                                float* __restrict__ ws) {
  int tid = blockIdx.x * blockDim.x + threadIdx.x;  // 65536 threads
  int d = tid & (kD - 1);
  int n = tid >> 10;
  float dt  = expf(log_dt[d]);
  float An  = -0.5f * (float)(n + 1);
  float dtA = dt * An;
  float a   = expf(dtA);
  float bbar = (expm1f(dtA) / An) * Bm[d * kN + n];
  float cb   = Cm[d * kN + n] * bbar;
  float aT   = expf(dtA * (float)kT);  // a^64
  ws[kAOff  + (long)n * kD + d] = a;
  ws[kCbOff + (long)n * kD + d] = cb;
  ws[kAtOff + (long)n * kD + d] = aT;
}

// Phase 1: chunk-local end states (zero initial state). R5-proven skeleton:
// xv[64] AGPR-parked, NG=8 h-chains share each xv read, single u write.
__global__ __launch_bounds__(256) void s4d_state_kernel(
    const float* __restrict__ x, float* __restrict__ ws) {
  int tid = blockIdx.x * blockDim.x + threadIdx.x;  // 262144 threads
  int d  = tid & (kD - 1);   // consecutive lanes -> consecutive d: coalesced
  int bc = tid >> 10;

  const float* xp = x + ((long)bc * kT) * kD + d;  // bc = b*kC + c
  float xv[kT];
#pragma unroll
  for (int t = 0; t < kT; ++t) xv[t] = xp[(long)t * kD];

  const float* ap = ws + kAOff + d;
  float* up = ws + ((long)bc * kN) * kD + d;
#pragma unroll 1
  for (int g = 0; g < kN; g += kNG) {
    float a[kNG], h[kNG];
#pragma unroll
    for (int i = 0; i < kNG; ++i) {
      a[i] = ap[(long)(g + i) * kD];
      h[i] = 0.f;
    }
#pragma unroll
    for (int t = 0; t < kT; ++t) {
      float xt = xv[t];
#pragma unroll
      for (int i = 0; i < kNG; ++i) h[i] = fmaf(h[i], a[i], xt);
    }
#pragma unroll
    for (int i = 0; i < kNG; ++i) up[(long)(g + i) * kD] = h[i];
  }
}

// Phase 2: inter-chunk scan (R5 verbatim). After this, ws[u-region] holds
// s_start[c] = state at the END of chunk c-1 (initial state for chunk c).
__global__ void s4d_scan_kernel(float* __restrict__ ws) {
  int tid = blockIdx.x * blockDim.x + threadIdx.x;  // 524288 threads
  int d  = tid & (kD - 1);
  int bn = tid >> 10;
  int n  = bn & (kN - 1);
  int b  = bn >> 6;
  float aT = ws[kAtOff + (long)n * kD + d];
  float* up = ws + ((long)b * kC * kN + n) * kD + d;
  const long cstride = (long)kN * kD;
  float s = 0.f;
#pragma unroll 1
  for (int c = 0; c < kC; ++c) {
    float u = up[(long)c * cstride];
    up[(long)c * cstride] = s;  // in place: u[c] -> s_start[c]
    s = fmaf(aT, s, u);
  }
}

// Phase 3: full output at T=32 half-chunks via intra-block producer-consumer
// pipeline. Block = 128 d x 2 roles; role = wave-uniform (waves 0-1 / 2-3).
// Role 0: half-chunk 2c, start from s64[c] (global); publishes ending h[8]
// per n-group to LDS. Role 1: half-chunk 2c+1, start from LDS, one phase
// behind. Double-buffered hbuf; 9 phases, 1 barrier each.
__global__ __launch_bounds__(256, 3) void s4d_out_kernel(
    const float* __restrict__ x, const float* __restrict__ Dv,
    float* __restrict__ y, const float* __restrict__ ws) {
  __shared__ float hbuf[2][kNG][128];  // 8 KB

  int tidx = threadIdx.x;
  int role = tidx >> 7;   // 0: first half, 1: second half (wave-uniform)
  int dloc = tidx & 127;
  int blk  = blockIdx.x;          // = (b*kC + c)*8 + dblk ; 2048 blocks
  int dblk = blk & 7;
  int bc   = blk >> 3;            // b*kC + c
  int d    = dblk * 128 + dloc;

  const float* xp =
      x + ((long)bc * kT + (long)role * kTO) * kD + d;
  float xv[kTO];
#pragma unroll
  for (int t = 0; t < kTO; ++t) xv[t] = xp[(long)t * kD];

  float Dd = Dv[d];
  float acc[kTO];
#pragma unroll
  for (int t = 0; t < kTO; ++t) acc[t] = Dd * xv[t];

  const float* ap  = ws + kAOff + d;
  const float* cbp = ws + kCbOff + d;
  const float* sp  = ws + ((long)bc * kN) * kD + d;  // s_start[c] (T=64)

#pragma unroll 1
  for (int p = 0; p <= kG; ++p) {
    if (p > 0) __syncthreads();  // uniform condition: all threads reach it
    if (role == 0) {
      if (p < kG) {
        int g = p * kNG;
        float a[kNG], cb[kNG], h[kNG];
#pragma unroll
        for (int i = 0; i < kNG; ++i) {
          long o = (long)(g + i) * kD;
          a[i]  = ap[o];
          cb[i] = cbp[o];
          h[i]  = sp[o];  // chunk-start state from scan
        }
#pragma unroll
        for (int t = 0; t < kTO; ++t) {
          float xt = xv[t];
          float s  = acc[t];
#pragma unroll
          for (int i = 0; i < kNG; ++i) {
            h[i] = fmaf(h[i], a[i], xt);
            s    = fmaf(cb[i], h[i], s);
          }
          acc[t] = s;
        }
#pragma unroll
        for (int i = 0; i < kNG; ++i) hbuf[p & 1][i][dloc] = h[i];
      }
    } else {
      if (p > 0) {
        int g = (p - 1) * kNG;
        float a[kNG], cb[kNG], h[kNG];
#pragma unroll
        for (int i = 0; i < kNG; ++i) {
          long o = (long)(g + i) * kD;
          a[i]  = ap[o];
          cb[i] = cbp[o];
          h[i]  = hbuf[(p - 1) & 1][i][dloc];  // role-0's ending state
        }
#pragma unroll
        for (int t = 0; t < kTO; ++t) {
          float xt = xv[t];
          float s  = acc[t];
#pragma unroll
          for (int i = 0; i < kNG; ++i) {
            h[i] = fmaf(h[i], a[i], xt);
            s    = fmaf(cb[i], h[i], s);
          }
          acc[t] = s;
        }
      }
    }
  }

  float* yp = y + ((long)bc * kT + (long)role * kTO) * kD + d;
#pragma unroll
  for (int t = 0; t < kTO; ++t) yp[(long)t * kD] = acc[t];
}

extern "C" void kernel_launch(void* const* d_in, const int* in_sizes, int n_in,
                              void* d_out, int out_size, void* d_ws,
                              size_t ws_size, hipStream_t stream) {
  const float* x      = (const float*)d_in[0];
  const float* log_dt = (const float*)d_in[1];
  const float* Bm     = (const float*)d_in[2];
  const float* Cm     = (const float*)d_in[3];
  const float* Dv     = (const float*)d_in[4];
  float* y  = (float*)d_out;
  float* ws = (float*)d_ws;

  hipLaunchKernelGGL(s4d_coef_kernel, dim3((kN * kD) / 256), dim3(256), 0,
                     stream, log_dt, Bm, Cm, ws);
  hipLaunchKernelGGL(s4d_state_kernel, dim3((kBatch * kC * kD) / 256),
                     dim3(256), 0, stream, x, ws);
  hipLaunchKernelGGL(s4d_scan_kernel, dim3((kBatch * kN * kD) / 256),
                     dim3(256), 0, stream, ws);
  hipLaunchKernelGGL(s4d_out_kernel, dim3(kBatch * kC * (kD / 128)),
                     dim3(256), 0, stream, x, Dv, y, ws);
}

// Round 8
// 226.840 us; speedup vs baseline: 1.1031x; 1.0372x over previous
//
#include <hip/hip_runtime.h>
#include <math.h>

// S4D forward (conv mode) via chunked linear recurrence.
// y[b,l,d] = D[d]*x[b,l,d] + sum_n CB[d,n] * h_n[l],  h_n[l] = a_n h_n[l-1] + x[l]
// a = exp(dt*A), CB = C * expm1(dt*A)/A * B, A_n = -0.5*(n+1)
//
// R7 post-mortem: identical non-out kernels measured 131.8 (R5) vs 148.9
// (R7) -> run noise +-17us; only structural traffic cuts are measurable.
// R8: store the u/s state region in BF16 (RTNE). Coefficient tables stay
// fp32 (they compound; states only feed the linear correction term --
// est. added error ~2e-3 << current 1.56e-2 absmax). This makes T=32
// affordable everywhere: u(T=32, bf16) = 67 MB == u(T=64, fp32), so
// state/scan traffic matches the best known while the out kernel is R6's
// proven direct-s T=32 form (70.7us measured): no mid-states, no pipeline.
//   state: T=32, NG=8, xv[32] AGPR-parked (R5-proven skeleton)
//   scan:  64 steps over bf16 u, fp32 carry chain
//   out:   R6's T=32/NG=8 skeleton, h-init from bf16 s
// ws: u 33,554,432 x bf16 (67,108,864 B) + 3 fp32 tables (786,432 B).

namespace {
constexpr int kBatch = 8;
constexpr int kLen   = 2048;
constexpr int kD     = 1024;
constexpr int kN     = 64;         // states
constexpr int kT     = 32;         // chunk length (everywhere)
constexpr int kC     = kLen / kT;  // 64 chunks
constexpr int kNG    = 8;          // n-group size

// u region: bf16, one entry per (b,c,n,d)
constexpr long kUElems = (long)kBatch * kC * kN * kD;  // 33,554,432
// fp32 tables live after the u region (u is 16,777,216 float-slots)
constexpr long kAOff  = kUElems / 2;              // a[n][d]   (float index)
constexpr long kCbOff = kAOff + (long)kN * kD;    // cb[n][d]
constexpr long kAtOff = kCbOff + (long)kN * kD;   // a^32[n][d]
// total ws: 67,108,864 + 786,432 = 67,895,296 B (~64.8 MiB)

__device__ __forceinline__ float bf2f(unsigned short v) {
  union { unsigned int u; float f; } c;
  c.u = (unsigned int)v << 16;
  return c.f;
}
__device__ __forceinline__ unsigned short f2bf(float f) {
  union { unsigned int u; float f; } c;
  c.f = f;
  unsigned int u = c.u + 0x7FFFu + ((c.u >> 16) & 1u);  // RTNE
  return (unsigned short)(u >> 16);
}
}  // namespace

__global__ void s4d_coef_kernel(const float* __restrict__ log_dt,
                                const float* __restrict__ Bm,
                                const float* __restrict__ Cm,
                                float* __restrict__ ws) {
  int tid = blockIdx.x * blockDim.x + threadIdx.x;  // 65536 threads
  int d = tid & (kD - 1);
  int n = tid >> 10;
  float dt  = expf(log_dt[d]);
  float An  = -0.5f * (float)(n + 1);
  float dtA = dt * An;
  float a   = expf(dtA);
  float bbar = (expm1f(dtA) / An) * Bm[d * kN + n];
  float cb   = Cm[d * kN + n] * bbar;
  float aT   = expf(dtA * (float)kT);  // a^32
  ws[kAOff  + (long)n * kD + d] = a;
  ws[kCbOff + (long)n * kD + d] = cb;
  ws[kAtOff + (long)n * kD + d] = aT;
}

// Phase 1: chunk-local end states (zero init), T=32. R5-proven skeleton:
// xv[32] AGPR-parked, NG=8 h-chains share each xv read; bf16 u stores.
__global__ __launch_bounds__(256) void s4d_state_kernel(
    const float* __restrict__ x, float* __restrict__ ws) {
  int tid = blockIdx.x * blockDim.x + threadIdx.x;  // 524288 threads
  int d  = tid & (kD - 1);   // consecutive lanes -> consecutive d: coalesced
  int bc = tid >> 10;        // b*kC + c, 0..511

  const float* xp = x + ((long)bc * kT) * kD + d;
  float xv[kT];
#pragma unroll
  for (int t = 0; t < kT; ++t) xv[t] = xp[(long)t * kD];

  const float* ap = ws + kAOff + d;
  unsigned short* up = (unsigned short*)ws + ((long)bc * kN) * kD + d;
#pragma unroll 1
  for (int g = 0; g < kN; g += kNG) {
    float a[kNG], h[kNG];
#pragma unroll
    for (int i = 0; i < kNG; ++i) {
      a[i] = ap[(long)(g + i) * kD];
      h[i] = 0.f;
    }
#pragma unroll
    for (int t = 0; t < kT; ++t) {
      float xt = xv[t];
#pragma unroll
      for (int i = 0; i < kNG; ++i) h[i] = fmaf(h[i], a[i], xt);
    }
#pragma unroll
    for (int i = 0; i < kNG; ++i) up[(long)(g + i) * kD] = f2bf(h[i]);
  }
}

// Phase 2: inter-chunk scan over bf16 u, fp32 carry. After this, the u
// region holds s_start[c] = state at the END of chunk c-1 (bf16).
__global__ void s4d_scan_kernel(float* __restrict__ ws) {
  int tid = blockIdx.x * blockDim.x + threadIdx.x;  // 524288 threads
  int d  = tid & (kD - 1);
  int bn = tid >> 10;
  int n  = bn & (kN - 1);
  int b  = bn >> 6;
  float aT = ws[kAtOff + (long)n * kD + d];
  unsigned short* up =
      (unsigned short*)ws + ((long)b * kC * kN + n) * kD + d;
  const long cstride = (long)kN * kD;
  float s = 0.f;
#pragma unroll 1
  for (int c = 0; c < kC; ++c) {
    float u = bf2f(up[(long)c * cstride]);
    up[(long)c * cstride] = f2bf(s);  // in place: u[c] -> s_start[c]
    s = fmaf(aT, s, u);
  }
}

// Phase 3: full output, T=32. R6's proven skeleton (xv[32]+acc[32]
// AGPR-parked, single-level NG=8 loop, direct s reads -- now bf16).
__global__ __launch_bounds__(256, 3) void s4d_out_kernel(
    const float* __restrict__ x, const float* __restrict__ Dv,
    float* __restrict__ y, const float* __restrict__ ws) {
  int tid = blockIdx.x * blockDim.x + threadIdx.x;  // 524288 threads
  int d  = tid & (kD - 1);
  int j  = tid >> 10;        // b*kC + c, 0..511

  const float* xp = x + ((long)j * kT) * kD + d;
  float xv[kT];
#pragma unroll
  for (int t = 0; t < kT; ++t) xv[t] = xp[(long)t * kD];

  float Dd = Dv[d];
  float acc[kT];
#pragma unroll
  for (int t = 0; t < kT; ++t) acc[t] = Dd * xv[t];

  const float* ap  = ws + kAOff + d;
  const float* cbp = ws + kCbOff + d;
  const unsigned short* sp =
      (const unsigned short*)ws + ((long)j * kN) * kD + d;

#pragma unroll 1
  for (int g = 0; g < kN; g += kNG) {
    float a[kNG], cb[kNG], h[kNG];
#pragma unroll
    for (int i = 0; i < kNG; ++i) {
      long o = (long)(g + i) * kD;
      a[i]  = ap[o];
      cb[i] = cbp[o];
      h[i]  = bf2f(sp[o]);  // start state for this chunk
    }
#pragma unroll
    for (int t = 0; t < kT; ++t) {
      float xt = xv[t];
      float s  = acc[t];
#pragma unroll
      for (int i = 0; i < kNG; ++i) {
        h[i] = fmaf(h[i], a[i], xt);
        s    = fmaf(cb[i], h[i], s);
      }
      acc[t] = s;
    }
  }

  float* yp = y + ((long)j * kT) * kD + d;
#pragma unroll
  for (int t = 0; t < kT; ++t) yp[(long)t * kD] = acc[t];
}

extern "C" void kernel_launch(void* const* d_in, const int* in_sizes, int n_in,
                              void* d_out, int out_size, void* d_ws,
                              size_t ws_size, hipStream_t stream) {
  const float* x      = (const float*)d_in[0];
  const float* log_dt = (const float*)d_in[1];
  const float* Bm     = (const float*)d_in[2];
  const float* Cm     = (const float*)d_in[3];
  const float* Dv     = (const float*)d_in[4];
  float* y  = (float*)d_out;
  float* ws = (float*)d_ws;

  hipLaunchKernelGGL(s4d_coef_kernel, dim3((kN * kD) / 256), dim3(256), 0,
                     stream, log_dt, Bm, Cm, ws);
  hipLaunchKernelGGL(s4d_state_kernel, dim3((kBatch * kC * kD) / 256),
                     dim3(256), 0, stream, x, ws);
  hipLaunchKernelGGL(s4d_scan_kernel, dim3((kBatch * kN * kD) / 256),
                     dim3(256), 0, stream, ws);
  hipLaunchKernelGGL(s4d_out_kernel, dim3((kBatch * kC * kD) / 256),
                     dim3(256), 0, stream, x, Dv, y, ws);
}

// Round 9
// 226.017 us; speedup vs baseline: 1.1071x; 1.0036x over previous
//
#include <hip/hip_runtime.h>
#include <math.h>

// S4D forward (conv mode) via chunked linear recurrence.
// y[b,l,d] = D[d]*x[b,l,d] + sum_n CB[d,n] * h_n[l],  h_n[l] = a_n h_n[l-1] + x[l]
// a = exp(dt*A), CB = C * expm1(dt*A)/A * B, A_n = -0.5*(n+1)
//
// R8 post-mortem: out at 72us, VALUBusy 65%. The 35% stall is group-boundary
// load latency: the 24 a/cb/s loads (4KB stride, ~600cy L2/L3) issue only
// after the previous group's t-loop (1024cy issue) completes ->
// 600/1624 = 37% predicted stall == measured. R9: rotating software
// prefetch of the NEXT n-group (R0-proven rotation pattern, parks cleanly)
// in out and state; next-u prefetch in scan. Prefetched bf16 s kept as raw
// ushort until the rotate so the waitcnt lands after the t-loop. Last-group
// prefetches over-read into the adjacent table regions (verified in-bounds
// of ws; values unused). Numerics bit-identical to R8.

namespace {
constexpr int kBatch = 8;
constexpr int kLen   = 2048;
constexpr int kD     = 1024;
constexpr int kN     = 64;         // states
constexpr int kT     = 32;         // chunk length (everywhere)
constexpr int kC     = kLen / kT;  // 64 chunks
constexpr int kNG    = 8;          // n-group size

// u region: bf16, one entry per (b,c,n,d)
constexpr long kUElems = (long)kBatch * kC * kN * kD;  // 33,554,432
// fp32 tables live after the u region (u is 16,777,216 float-slots)
constexpr long kAOff  = kUElems / 2;              // a[n][d]   (float index)
constexpr long kCbOff = kAOff + (long)kN * kD;    // cb[n][d]
constexpr long kAtOff = kCbOff + (long)kN * kD;   // a^32[n][d]
// total ws: 67,108,864 + 786,432 = 67,895,296 B (~64.8 MiB)

__device__ __forceinline__ float bf2f(unsigned short v) {
  union { unsigned int u; float f; } c;
  c.u = (unsigned int)v << 16;
  return c.f;
}
__device__ __forceinline__ unsigned short f2bf(float f) {
  union { unsigned int u; float f; } c;
  c.f = f;
  unsigned int u = c.u + 0x7FFFu + ((c.u >> 16) & 1u);  // RTNE
  return (unsigned short)(u >> 16);
}
}  // namespace

__global__ void s4d_coef_kernel(const float* __restrict__ log_dt,
                                const float* __restrict__ Bm,
                                const float* __restrict__ Cm,
                                float* __restrict__ ws) {
  int tid = blockIdx.x * blockDim.x + threadIdx.x;  // 65536 threads
  int d = tid & (kD - 1);
  int n = tid >> 10;
  float dt  = expf(log_dt[d]);
  float An  = -0.5f * (float)(n + 1);
  float dtA = dt * An;
  float a   = expf(dtA);
  float bbar = (expm1f(dtA) / An) * Bm[d * kN + n];
  float cb   = Cm[d * kN + n] * bbar;
  float aT   = expf(dtA * (float)kT);  // a^32
  ws[kAOff  + (long)n * kD + d] = a;
  ws[kCbOff + (long)n * kD + d] = cb;
  ws[kAtOff + (long)n * kD + d] = aT;
}

// Phase 1: chunk-local end states (zero init), T=32, NG=8, with rotating
// prefetch of the next a-group. xv[32] AGPR-parked (proven skeleton).
__global__ __launch_bounds__(256) void s4d_state_kernel(
    const float* __restrict__ x, float* __restrict__ ws) {
  int tid = blockIdx.x * blockDim.x + threadIdx.x;  // 524288 threads
  int d  = tid & (kD - 1);   // consecutive lanes -> consecutive d: coalesced
  int bc = tid >> 10;        // b*kC + c, 0..511

  const float* xp = x + ((long)bc * kT) * kD + d;
  float xv[kT];
#pragma unroll
  for (int t = 0; t < kT; ++t) xv[t] = xp[(long)t * kD];

  const float* ap = ws + kAOff + d;
  unsigned short* up = (unsigned short*)ws + ((long)bc * kN) * kD + d;

  float ca[kNG];
#pragma unroll
  for (int i = 0; i < kNG; ++i) ca[i] = ap[(long)i * kD];

#pragma unroll 1
  for (int g = 0; g < kN; g += kNG) {
    float na[kNG];
#pragma unroll
    for (int i = 0; i < kNG; ++i)
      na[i] = ap[(long)(g + kNG + i) * kD];  // last iter: cb region, unused
    float h[kNG];
#pragma unroll
    for (int i = 0; i < kNG; ++i) h[i] = 0.f;
#pragma unroll
    for (int t = 0; t < kT; ++t) {
      float xt = xv[t];
#pragma unroll
      for (int i = 0; i < kNG; ++i) h[i] = fmaf(h[i], ca[i], xt);
    }
#pragma unroll
    for (int i = 0; i < kNG; ++i) up[(long)(g + i) * kD] = f2bf(h[i]);
#pragma unroll
    for (int i = 0; i < kNG; ++i) ca[i] = na[i];
  }
}

// Phase 2: inter-chunk scan over bf16 u, fp32 carry, next-u prefetch.
// After this, the u region holds s_start[c] (bf16).
__global__ void s4d_scan_kernel(float* __restrict__ ws) {
  int tid = blockIdx.x * blockDim.x + threadIdx.x;  // 524288 threads
  int d  = tid & (kD - 1);
  int bn = tid >> 10;
  int n  = bn & (kN - 1);
  int b  = bn >> 6;
  float aT = ws[kAtOff + (long)n * kD + d];
  unsigned short* up =
      (unsigned short*)ws + ((long)b * kC * kN + n) * kD + d;
  const long cstride = (long)kN * kD;
  float s = 0.f;
  unsigned short uraw = up[0];
#pragma unroll 1
  for (int c = 0; c < kC; ++c) {
    // c = kC-1 prefetch over-reads into the fp32 tables (in-bounds, unused)
    unsigned short unext = up[(long)(c + 1) * cstride];
    float u = bf2f(uraw);
    up[(long)c * cstride] = f2bf(s);  // in place: u[c] -> s_start[c]
    s = fmaf(aT, s, u);
    uraw = unext;
  }
}

// Phase 3: full output, T=32, NG=8, rotating prefetch of the next group's
// a/cb/s (s kept raw ushort until the rotate so the waitcnt lands after
// the t-loop). xv[32]+acc[32] AGPR-parked (proven skeleton).
__global__ __launch_bounds__(256, 3) void s4d_out_kernel(
    const float* __restrict__ x, const float* __restrict__ Dv,
    float* __restrict__ y, const float* __restrict__ ws) {
  int tid = blockIdx.x * blockDim.x + threadIdx.x;  // 524288 threads
  int d  = tid & (kD - 1);
  int j  = tid >> 10;        // b*kC + c, 0..511

  const float* xp = x + ((long)j * kT) * kD + d;
  float xv[kT];
#pragma unroll
  for (int t = 0; t < kT; ++t) xv[t] = xp[(long)t * kD];

  float Dd = Dv[d];
  float acc[kT];
#pragma unroll
  for (int t = 0; t < kT; ++t) acc[t] = Dd * xv[t];

  const float* ap  = ws + kAOff + d;
  const float* cbp = ws + kCbOff + d;
  const unsigned short* sp =
      (const unsigned short*)ws + ((long)j * kN) * kD + d;

  float ca[kNG], ccb[kNG], ch[kNG];
#pragma unroll
  for (int i = 0; i < kNG; ++i) {
    long o = (long)i * kD;
    ca[i]  = ap[o];
    ccb[i] = cbp[o];
    ch[i]  = bf2f(sp[o]);
  }

#pragma unroll 1
  for (int g = 0; g < kN; g += kNG) {
    float na[kNG], ncb[kNG];
    unsigned short nhraw[kNG];
#pragma unroll
    for (int i = 0; i < kNG; ++i) {
      long o = (long)(g + kNG + i) * kD;  // last iter: adjacent regions,
      na[i]    = ap[o];                   // in-bounds of ws, unused
      ncb[i]   = cbp[o];
      nhraw[i] = sp[o];
    }
#pragma unroll
    for (int t = 0; t < kT; ++t) {
      float xt = xv[t];
      float s  = acc[t];
#pragma unroll
      for (int i = 0; i < kNG; ++i) {
        ch[i] = fmaf(ch[i], ca[i], xt);
        s     = fmaf(ccb[i], ch[i], s);
      }
      acc[t] = s;
    }
#pragma unroll
    for (int i = 0; i < kNG; ++i) {
      ca[i]  = na[i];
      ccb[i] = ncb[i];
      ch[i]  = bf2f(nhraw[i]);
    }
  }

  float* yp = y + ((long)j * kT) * kD + d;
#pragma unroll
  for (int t = 0; t < kT; ++t) yp[(long)t * kD] = acc[t];
}

extern "C" void kernel_launch(void* const* d_in, const int* in_sizes, int n_in,
                              void* d_out, int out_size, void* d_ws,
                              size_t ws_size, hipStream_t stream) {
  const float* x      = (const float*)d_in[0];
  const float* log_dt = (const float*)d_in[1];
  const float* Bm     = (const float*)d_in[2];
  const float* Cm     = (const float*)d_in[3];
  const float* Dv     = (const float*)d_in[4];
  float* y  = (float*)d_out;
  float* ws = (float*)d_ws;

  hipLaunchKernelGGL(s4d_coef_kernel, dim3((kN * kD) / 256), dim3(256), 0,
                     stream, log_dt, Bm, Cm, ws);
  hipLaunchKernelGGL(s4d_state_kernel, dim3((kBatch * kC * kD) / 256),
                     dim3(256), 0, stream, x, ws);
  hipLaunchKernelGGL(s4d_scan_kernel, dim3((kBatch * kN * kD) / 256),
                     dim3(256), 0, stream, ws);
  hipLaunchKernelGGL(s4d_out_kernel, dim3((kBatch * kC * kD) / 256),
                     dim3(256), 0, stream, x, Dv, y, ws);
}